// Round 5
// baseline (510.113 us; speedup 1.0000x reference)
//
#include <hip/hip_runtime.h>

// GCNDecoder: B=2, N=40000, HID=128, E=640000, IN=3, OUT=3. Float tensors f32; indices int32.
//
// Round 5 changes vs round 4 (510 us, spmm 5x51 us dominant, FETCH 134 MB vs 20.5 MB array):
//   - final layer: project rA to 3 ch FIRST (spmm linear over channels) -> 16 B/edge gather
//   - spmm batch-split: one batch per block (blockIdx&1 -> XCD parity) halves per-XCD WS
//   - CSR build buckets each row's edges by col>>13 (5 tiles ~2 MB) -> L2-sized access frontier

typedef unsigned short u16;
typedef unsigned int   u32;
typedef __bf16 bf8_t __attribute__((ext_vector_type(8)));
typedef float  f4_t  __attribute__((ext_vector_type(4)));

#define N_NODES 40000
#define N_EDGES 640000
#define BN      80000            // BATCH * N_NODES
#define SCAN_N  320000           // N_NODES * 8 tile slots

__device__ __forceinline__ float bf2f(u16 u) {
  union { u32 i; float f; } v; v.i = ((u32)u) << 16; return v.f;
}
__device__ __forceinline__ u16 f2bf(float f) {
  union { float f; u32 i; } v; v.f = f;
  u32 i = v.i;
  return (u16)((i + 0x7FFFu + ((i >> 16) & 1u)) >> 16);   // RNE
}
__device__ __forceinline__ float asf(u32 i) {
  union { u32 u; float f; } v; v.u = i; return v.f;
}
__device__ __forceinline__ u32 pack2(float a, float b) {
  return (u32)f2bf(a) | ((u32)f2bf(b) << 16);
}

__global__ void fill_kernel(float* __restrict__ out, int n, float v) {
  int i = blockIdx.x * 256 + threadIdx.x;
  if (i < n) out[i] = v;
}

// ---------------- CSR build with col-tile buckets (tile = col>>13, 5 used of 8 slots) ----------------
__global__ void hist2_kernel(const int* __restrict__ rows, const int* __restrict__ cols,
                             int* __restrict__ cnt2) {
  int e = blockIdx.x * 256 + threadIdx.x;
  if (e < N_EDGES) {
    int t = cols[e] >> 13;
    atomicAdd(&cnt2[rows[e] * 8 + t], 1);
  }
}

// phase A: totals per 2048-entry chunk
__global__ void scanA_kernel(const int* __restrict__ cnt2, int* __restrict__ blocksum) {
  __shared__ int sm[256];
  int t = threadIdx.x;
  int base = blockIdx.x * 2048 + t * 8;
  int s = 0;
#pragma unroll
  for (int i = 0; i < 8; ++i) { int idx = base + i; if (idx < SCAN_N) s += cnt2[idx]; }
  sm[t] = s; __syncthreads();
  for (int off = 128; off > 0; off >>= 1) {
    if (t < off) sm[t] += sm[t + off];
    __syncthreads();
  }
  if (t == 0) blocksum[blockIdx.x] = sm[0];
}

// phase B: exclusive scan of chunk totals (nblk <= 256)
__global__ void scanB_kernel(int* __restrict__ blocksum, int nblk) {
  __shared__ int sm[256];
  int t = threadIdx.x;
  int v = (t < nblk) ? blocksum[t] : 0;
  sm[t] = v; __syncthreads();
  for (int off = 1; off < 256; off <<= 1) {
    int u = (t >= off) ? sm[t - off] : 0;
    __syncthreads();
    sm[t] += u;
    __syncthreads();
  }
  if (t < nblk) blocksum[t] = sm[t] - v;
}

// phase C: in-place entry-level exclusive prefix (cnt2 becomes start offsets / scatter cursors)
__global__ void scanC_kernel(int* __restrict__ cnt2, const int* __restrict__ blocksum) {
  __shared__ int sm[256];
  int t = threadIdx.x;
  int base = blockIdx.x * 2048 + t * 8;
  int v[8]; int s = 0;
#pragma unroll
  for (int i = 0; i < 8; ++i) { int idx = base + i; v[i] = (idx < SCAN_N) ? cnt2[idx] : 0; s += v[i]; }
  sm[t] = s; __syncthreads();
  for (int off = 1; off < 256; off <<= 1) {
    int u = (t >= off) ? sm[t - off] : 0;
    __syncthreads();
    sm[t] += u;
    __syncthreads();
  }
  int run = blocksum[blockIdx.x] + sm[t] - s;
#pragma unroll
  for (int i = 0; i < 8; ++i) {
    int idx = base + i;
    if (idx < SCAN_N) { int c = v[i]; cnt2[idx] = run; run += c; }
  }
}

__global__ void rowptr_kernel(const int* __restrict__ cnt2, int* __restrict__ row_ptr) {
  int r = blockIdx.x * 256 + threadIdx.x;
  if (r < N_NODES) row_ptr[r] = cnt2[r * 8];
  if (r == 0) row_ptr[N_NODES] = N_EDGES;
}

__global__ void scatter2_kernel(const int* __restrict__ rows, const int* __restrict__ cols,
                                int* __restrict__ cur2, int* __restrict__ cols_s) {
  int e = blockIdx.x * 256 + threadIdx.x;
  if (e < N_EDGES) {
    int c = cols[e];
    int t = c >> 13;
    int pos = atomicAdd(&cur2[rows[e] * 8 + t], 1);
    cols_s[pos] = c;
  }
}

// ---------------- weight prep: WtCat[g][h][k] = bf16(k<128 ? Ws[g][k][h] : Wf[g][k-128][h]) ----------------
__global__ void wprep_kernel(const float* __restrict__ Wf_b, const float* __restrict__ Ws_b,
                             const float* __restrict__ bf_b, const float* __restrict__ bs_b,
                             u16* __restrict__ WtCat, float* __restrict__ biasCat) {
  int idx = blockIdx.x * 256 + threadIdx.x;      // 4*128*256 = 131072
  int g = idx >> 15, rem = idx & 32767;
  int h = rem >> 8, k = rem & 255;
  float v = (k < 128) ? Ws_b[(g * 128 + k) * 128 + h]
                      : Wf_b[(g * 128 + (k - 128)) * 128 + h];
  WtCat[idx] = f2bf(v);                           // idx == g*32768 + h*256 + k
  if (k == 0) biasCat[g * 128 + h] = bs_b[g * 128 + h] + bf_b[g * 128 + h];
}

// ---------------- xb = p @ W_init + b_init (bf16) ; rA = relu(xb) ----------------
__global__ void init_kernel(const float* __restrict__ p, const float* __restrict__ W,
                            const float* __restrict__ bias, u16* __restrict__ xb,
                            u16* __restrict__ rA) {
  int idx = blockIdx.x * 256 + threadIdx.x;      // BN*64 = 5,120,000
  int row = idx >> 6;
  int h = (idx & 63) * 2;
  float p0 = p[row * 3], p1 = p[row * 3 + 1], p2 = p[row * 3 + 2];
  float s0 = p0 * W[h]     + p1 * W[128 + h]     + p2 * W[256 + h]     + bias[h];
  float s1 = p0 * W[h + 1] + p1 * W[128 + h + 1] + p2 * W[256 + h + 1] + bias[h + 1];
  size_t o = (size_t)row * 64 + (h >> 1);
  ((u32*)xb)[o] = pack2(s0, s1);
  ((u32*)rA)[o] = pack2(s0 > 0.f ? s0 : 0.f, s1 > 0.f ? s1 : 0.f);
}

// ---------------- gather SPMM: y[b][r][:] = (1/deg) * sum_e x[b][col[e]][:] ----------------
// one wave per (row, batch); batch = blockIdx&1 (XCD parity split); u32 (2ch) per lane per edge
__global__ void spmm_kernel(const int* __restrict__ row_ptr, const int* __restrict__ cols_s,
                            const u16* __restrict__ xin, u16* __restrict__ yout) {
  int b = blockIdx.x & 1;
  int row = (blockIdx.x >> 1) * 4 + (threadIdx.x >> 6);
  int l = threadIdx.x & 63;
  int s = row_ptr[row], e = row_ptr[row + 1];
  const u32* X = (const u32*)xin + (size_t)b * 2560000 + l;
  float a0 = 0.f, a1 = 0.f;
  int i = s;
  for (; i + 3 < e; i += 4) {
    int c0 = cols_s[i], c1 = cols_s[i + 1], c2 = cols_s[i + 2], c3 = cols_s[i + 3];
    u32 u0 = X[c0 * 64], u1 = X[c1 * 64], u2 = X[c2 * 64], u3 = X[c3 * 64];
    a0 += asf(u0 << 16); a1 += asf(u0 & 0xffff0000u);
    a0 += asf(u1 << 16); a1 += asf(u1 & 0xffff0000u);
    a0 += asf(u2 << 16); a1 += asf(u2 & 0xffff0000u);
    a0 += asf(u3 << 16); a1 += asf(u3 & 0xffff0000u);
  }
  for (; i < e; ++i) {
    u32 u = X[cols_s[i] * 64];
    a0 += asf(u << 16); a1 += asf(u & 0xffff0000u);
  }
  float scale = (e > s) ? 1.f / (float)(e - s) : 0.f;
  ((u32*)yout)[(size_t)b * 2560000 + (size_t)row * 64 + l] = pack2(a0 * scale, a1 * scale);
}

// ---------------- fused gconv GEMM: [rA | y] (M x 256) @ WtCat[g]^T (256 x 128) + bias ----------------
// MODE 0: rout = relu(acc+bias)     MODE 1: xb += acc+bias (bf16 residual); rout = relu(xb)
template <int MODE>
__global__ __launch_bounds__(256, 2) void gemm_kernel(
    const u16* __restrict__ rin, const u16* __restrict__ yin,
    const u16* __restrict__ WtCat, const float* __restrict__ biasCat, int g,
    u16* __restrict__ rout, u16* __restrict__ xresid) {
  __shared__ __align__(16) u16 ldsA[128 * 72];   // 128 rows x 64 k, pad to 72
  __shared__ __align__(16) u16 ldsW[128 * 72];
  int tid = threadIdx.x;
  int m0 = blockIdx.x * 128;
  int li = tid & 15, q = (tid >> 4) & 3, wv = tid >> 6;
  int wmo = (wv >> 1) * 64, wno = (wv & 1) * 64;

  f4_t acc[4][4];
#pragma unroll
  for (int i = 0; i < 4; ++i)
#pragma unroll
    for (int j = 0; j < 4; ++j) acc[i][j] = (f4_t){0.f, 0.f, 0.f, 0.f};

  const u16* Wsrc = WtCat + (size_t)g * 32768;

  for (int kb = 0; kb < 256; kb += 64) {
    __syncthreads();
    const u16* srcA = (kb < 128) ? (rin + kb) : (yin + (kb - 128));
#pragma unroll
    for (int p2 = 0; p2 < 4; ++p2) {
      int idx = p2 * 256 + tid;                  // 0..1023
      int row = idx >> 3, seg = idx & 7;         // 8 segs x 8 bf16 = 64 k
      uint4 va = *reinterpret_cast<const uint4*>(srcA + (size_t)(m0 + row) * 128 + seg * 8);
      *reinterpret_cast<uint4*>(&ldsA[row * 72 + seg * 8]) = va;
      uint4 vw = *reinterpret_cast<const uint4*>(Wsrc + (size_t)row * 256 + kb + seg * 8);
      *reinterpret_cast<uint4*>(&ldsW[row * 72 + seg * 8]) = vw;
    }
    __syncthreads();
#pragma unroll
    for (int kk = 0; kk < 64; kk += 32) {
      bf8_t af[4], wf[4];
#pragma unroll
      for (int t = 0; t < 4; ++t)
        af[t] = __builtin_bit_cast(bf8_t,
            *reinterpret_cast<const uint4*>(&ldsA[(wmo + t * 16 + li) * 72 + kk + q * 8]));
#pragma unroll
      for (int t = 0; t < 4; ++t)
        wf[t] = __builtin_bit_cast(bf8_t,
            *reinterpret_cast<const uint4*>(&ldsW[(wno + t * 16 + li) * 72 + kk + q * 8]));
#pragma unroll
      for (int i = 0; i < 4; ++i)
#pragma unroll
        for (int j = 0; j < 4; ++j)
          acc[i][j] = __builtin_amdgcn_mfma_f32_16x16x32_bf16(af[i], wf[j], acc[i][j], 0, 0, 0);
    }
  }

  float bias[4];
#pragma unroll
  for (int j = 0; j < 4; ++j) bias[j] = biasCat[g * 128 + wno + j * 16 + li];

#pragma unroll
  for (int i = 0; i < 4; ++i)
#pragma unroll
    for (int j = 0; j < 4; ++j)
#pragma unroll
      for (int r2 = 0; r2 < 4; ++r2) {
        int m = m0 + wmo + i * 16 + q * 4 + r2;
        int col = wno + j * 16 + li;
        float c = acc[i][j][r2] + bias[j];
        size_t id = (size_t)m * 128 + col;
        if (MODE == 0) {
          rout[id] = f2bf(c > 0.f ? c : 0.f);
        } else {
          float xn = bf2f(xresid[id]) + c;
          xresid[id] = f2bf(xn);
          rout[id] = f2bf(xn > 0.f ? xn : 0.f);
        }
      }
}

// ---------------- final layer projections: zf = rA@Wf_o, zs = rA@Ws_o + bs + bf (wave/row) ----------------
__global__ void zproj_kernel(const u16* __restrict__ rA,
                             const float* __restrict__ Wfo, const float* __restrict__ Wso,
                             const float* __restrict__ bfo, const float* __restrict__ bso,
                             float4* __restrict__ zf4, float4* __restrict__ zs4) {
  int row = blockIdx.x * 4 + (threadIdx.x >> 6);
  int l = threadIdx.x & 63;
  u32 ra = ((const u32*)rA)[(size_t)row * 64 + l];
  float r0 = asf(ra << 16), r1 = asf(ra & 0xffff0000u);
  int ch = l * 2;
  float f0 = r0 * Wfo[ch * 3 + 0] + r1 * Wfo[ch * 3 + 3];
  float f1 = r0 * Wfo[ch * 3 + 1] + r1 * Wfo[ch * 3 + 4];
  float f2 = r0 * Wfo[ch * 3 + 2] + r1 * Wfo[ch * 3 + 5];
  float s0 = r0 * Wso[ch * 3 + 0] + r1 * Wso[ch * 3 + 3];
  float s1 = r0 * Wso[ch * 3 + 1] + r1 * Wso[ch * 3 + 4];
  float s2 = r0 * Wso[ch * 3 + 2] + r1 * Wso[ch * 3 + 5];
#pragma unroll
  for (int off = 32; off >= 1; off >>= 1) {
    f0 += __shfl_down(f0, off); f1 += __shfl_down(f1, off); f2 += __shfl_down(f2, off);
    s0 += __shfl_down(s0, off); s1 += __shfl_down(s1, off); s2 += __shfl_down(s2, off);
  }
  if (l == 0) {
    zf4[row] = make_float4(f0, f1, f2, 0.f);
    zs4[row] = make_float4(s0 + bso[0] + bfo[0], s1 + bso[1] + bfo[1], s2 + bso[2] + bfo[2], 0.f);
  }
}

// ---------------- 3-channel spmm + add: out[row] = zs[row] + (1/deg) * sum zf[col] ----------------
__global__ void spmm3_kernel(const int* __restrict__ row_ptr, const int* __restrict__ cols_s,
                             const float4* __restrict__ zf4, const float4* __restrict__ zs4,
                             float* __restrict__ out) {
  int idx = blockIdx.x * 256 + threadIdx.x;
  if (idx >= BN) return;
  int b = (idx >= N_NODES) ? 1 : 0;
  int r = idx - b * N_NODES;
  int s = row_ptr[r], e = row_ptr[r + 1];
  const float4* Z = zf4 + (size_t)b * N_NODES;
  float a0 = 0.f, a1 = 0.f, a2 = 0.f;
  for (int i = s; i < e; ++i) {
    float4 z = Z[cols_s[i]];
    a0 += z.x; a1 += z.y; a2 += z.z;
  }
  float sc = (e > s) ? 1.f / (float)(e - s) : 0.f;
  float4 zs = zs4[idx];
  out[idx * 3 + 0] = zs.x + a0 * sc;
  out[idx * 3 + 1] = zs.y + a1 * sc;
  out[idx * 3 + 2] = zs.z + a2 * sc;
}

extern "C" void kernel_launch(void* const* d_in, const int* in_sizes, int n_in,
                              void* d_out, int out_size, void* d_ws, size_t ws_size,
                              hipStream_t stream) {
  float* out = (float*)d_out;
  int fill_grid = (out_size + 255) / 256;

  const int exp_sizes[14] = {240000, 640000, 640000, 640000, 384, 128,
                             65536, 512, 65536, 512, 384, 3, 384, 3};
  bool sizes_ok = (n_in == 14);
  if (sizes_ok) for (int i = 0; i < 14; ++i) if (in_sizes[i] != exp_sizes[i]) sizes_ok = false;
  if (!sizes_ok) {
    fill_kernel<<<fill_grid, 256, 0, stream>>>(out, out_size, 1.0f);
    return;
  }

  // ws: 4*20,480,000 + 2,560,000 + 160,016 + 1,280,000 + 1,024 + 262,144 + 2,048 = 86,185,232 B
  const size_t NEED = (size_t)4 * BN * 128 * 2 + (size_t)N_EDGES * 4 + 160016
                    + (size_t)N_NODES * 8 * 4 + 1024 + 262144 + 2048;
  if (ws_size < NEED) {
    fill_kernel<<<fill_grid, 256, 0, stream>>>(out, out_size, 0.0f);
    return;
  }

  const float* p      = (const float*)d_in[0];
  const int*   erows  = (const int*)d_in[2];
  const int*   ecols  = (const int*)d_in[3];
  const float* W_init = (const float*)d_in[4];
  const float* b_init = (const float*)d_in[5];
  const float* Wf_b   = (const float*)d_in[6];
  const float* bf_b   = (const float*)d_in[7];
  const float* Ws_b   = (const float*)d_in[8];
  const float* bs_b   = (const float*)d_in[9];
  const float* Wf_o   = (const float*)d_in[10];
  const float* bf_o   = (const float*)d_in[11];
  const float* Ws_o   = (const float*)d_in[12];
  const float* bs_o   = (const float*)d_in[13];

  char* w = (char*)d_ws;
  u16*   rA       = (u16*)w;   w += (size_t)BN * 128 * 2;       // 20,480,000
  u16*   rB       = (u16*)w;   w += (size_t)BN * 128 * 2;
  u16*   y        = (u16*)w;   w += (size_t)BN * 128 * 2;       // zf4/zs4 alias (y dead by then)
  u16*   xb       = (u16*)w;   w += (size_t)BN * 128 * 2;       // bf16 residual
  int*   cols_s   = (int*)w;   w += (size_t)N_EDGES * 4;
  int*   row_ptr  = (int*)w;   w += 160016;                     // 40001 ints (padded)
  int*   cnt2     = (int*)w;   w += (size_t)N_NODES * 8 * 4;    // 1,280,000 (hist/cursors)
  int*   blocksum = (int*)w;   w += 1024;                       // 157 ints (padded)
  u16*   WtCat    = (u16*)w;   w += 4 * 128 * 256 * 2;          // 262,144
  float* biasCat  = (float*)w; w += 4 * 128 * 4;

  float4* zf4 = (float4*)y;                                     // 1,280,000 B
  float4* zs4 = (float4*)(y + 640000);                          // next 1,280,000 B

  const int SBLK = (SCAN_N + 2047) / 2048;                      // 157

  hipMemsetAsync(cnt2, 0, (size_t)N_NODES * 8 * 4, stream);
  hist2_kernel<<<2500, 256, 0, stream>>>(erows, ecols, cnt2);
  scanA_kernel<<<SBLK, 256, 0, stream>>>(cnt2, blocksum);
  scanB_kernel<<<1, 256, 0, stream>>>(blocksum, SBLK);
  scanC_kernel<<<SBLK, 256, 0, stream>>>(cnt2, blocksum);
  rowptr_kernel<<<157, 256, 0, stream>>>(cnt2, row_ptr);
  scatter2_kernel<<<2500, 256, 0, stream>>>(erows, ecols, cnt2, cols_s);
  wprep_kernel<<<512, 256, 0, stream>>>(Wf_b, Ws_b, bf_b, bs_b, WtCat, biasCat);
  init_kernel<<<20000, 256, 0, stream>>>(p, W_init, b_init, xb, rA);

  for (int blk = 0; blk < 2; ++blk) {
    spmm_kernel<<<20000, 256, 0, stream>>>(row_ptr, cols_s, rA, y);
    gemm_kernel<0><<<625, 256, 0, stream>>>(rA, y, WtCat, biasCat, 2 * blk, rB, nullptr);
    spmm_kernel<<<20000, 256, 0, stream>>>(row_ptr, cols_s, rB, y);
    gemm_kernel<1><<<625, 256, 0, stream>>>(rB, y, WtCat, biasCat, 2 * blk + 1, rA, xb);
  }
  zproj_kernel<<<20000, 256, 0, stream>>>(rA, Wf_o, Ws_o, bf_o, bs_o, zf4, zs4);
  spmm3_kernel<<<(BN + 255) / 256, 256, 0, stream>>>(row_ptr, cols_s, zf4, zs4, out);
}